// Round 11
// baseline (154.186 us; speedup 1.0000x reference)
//
#include <hip/hip_runtime.h>
#include <hip/hip_bf16.h>
#include <math.h>

// Mean-shift as attention. Round 11 = round-10 structure with ONE change:
// exp2 computed as a degree-6 VALU polynomial (6 v_fma_f32) instead of
// v_exp_f32 (TRANS pipe). Theory: k_ms's unexplained 4x over the per-SIMD
// pipe floor is transcendental-throughput saturation; s is bounded in
// [-0.8,0.8] (bw*log2e*<x_i,x_j>, contracting), so Taylor-6 has rel err
// <=2e-5 -- invisible under bf16 P rounding (2e-3).

typedef short bf16x8 __attribute__((ext_vector_type(8)));
typedef float f32x16 __attribute__((ext_vector_type(16)));
typedef int v2i __attribute__((ext_vector_type(2)));

#define NPIX 8192
#define DIM 32
#define NITER 5
#define SCH 16                // i-chunks (grid.y)
#define CHUNK (NPIX / SCH)    // 512 i per WG
#define HALF 128              // i per LDS stage
#define HALVES (CHUNK / HALF) // 4
#define WAVES 4               // waves per WG (128 j per WG)
#define ALPHA 0.8493219f      // sqrt(0.5 * log2(e))

// exp2(s) for s in ~[-1.2, 1.2]: Taylor of e^(s ln2), degree 6, on VALU.
__device__ __forceinline__ float exp2poly(float s) {
    const float c1 = 0.69314718f, c2 = 0.24022651f, c3 = 0.05550411f,
                c4 = 0.00961813f, c5 = 0.00133336f, c6 = 0.00015404f;
    float p = fmaf(s, c6, c5);
    p = fmaf(p, s, c4);
    p = fmaf(p, s, c3);
    p = fmaf(p, s, c2);
    p = fmaf(p, s, c1);
    p = fmaf(p, s, 1.0f);
    return p;
}

__device__ __forceinline__ void glds16(const uint4* g, uint4* l) {
#if __has_builtin(__builtin_amdgcn_global_load_lds)
    __builtin_amdgcn_global_load_lds((const __attribute__((address_space(1))) void*)g,
                                     (__attribute__((address_space(3))) void*)l,
                                     16, 0, 0);
#else
    *l = *g;
#endif
}

__device__ inline unsigned cvtpk(float lo, float hi) {
    unsigned r;
    asm("v_cvt_pk_bf16_f32 %0, %1, %2" : "=v"(r) : "v"(lo), "v"(hi));
    return r;
}

__device__ inline void swap32(unsigned a, unsigned b, unsigned& x, unsigned& y) {
#if __has_builtin(__builtin_amdgcn_permlane32_swap)
    v2i r = __builtin_amdgcn_permlane32_swap((int)a, (int)b, false, false);
    x = (unsigned)r.x;
    y = (unsigned)r.y;
#else
    unsigned bs = __shfl_xor(b, 32);
    unsigned as = __shfl_xor(a, 32);
    int hi = (int)(threadIdx.x & 63) >> 5;
    x = hi ? bs : a;
    y = hi ? b : as;
#endif
}

__device__ inline unsigned short f2bf(float f) {  // RNE
    unsigned u = __float_as_uint(f);
    unsigned r = (u + 0x7FFFu + ((u >> 16) & 1u)) >> 16;
    return (unsigned short)r;
}

__device__ inline unsigned pk2(float a, float b) {
    return (unsigned)f2bf(a) | ((unsigned)f2bf(b) << 16);
}

union U4 { uint4 q; bf16x8 v; };

// ---------------- main pair kernel ----------------
__global__ __launch_bounds__(256, 4) void k_ms(const unsigned short* __restrict__ kq,
                                               const unsigned short* __restrict__ vv,
                                               float* __restrict__ party,
                                               float* __restrict__ partd) {
    __shared__ uint4 sm[2048];  // 2 bufs x (K 512 | V 512) uint4 = 32 KB
    const int tid = threadIdx.x;
    const int lane = tid & 63;
    const int lo = lane & 31, hi = lane >> 5;
    const int wv = tid >> 6;
    const int wbase = tid & ~63;
    const int jblk = blockIdx.x * WAVES + wv;   // 0..255
    const int chunk = blockIdx.y;               // 0..SCH-1

    const uint4* kq4 = (const uint4*)kq;
    const uint4* vv4 = (const uint4*)vv;

    U4 q0, q1;
    q0.q = kq4[jblk * 128 + lane];
    q1.q = kq4[jblk * 128 + 64 + lane];

    U4 ones;
    ones.q = make_uint4(0x3F803F80u, 0x3F803F80u, 0x3F803F80u, 0x3F803F80u);

    f32x16 z16;
#pragma unroll
    for (int r = 0; r < 16; ++r) z16[r] = 0.f;
    f32x16 y = z16;
    f32x16 dg16 = z16;

    const uint4* gk = kq4 + (size_t)chunk * CHUNK * 4;   // 64 B per i
    const uint4* gv = vv4 + (size_t)chunk * CHUNK * 4;

    auto STAGE = [&](int h, int b) {
        const uint4* gkh = gk + h * (HALF * 4);
        const uint4* gvh = gv + h * (HALF * 4);
        uint4* dK = sm + b * 1024 + wbase;   // wave-uniform LDS base
        uint4* dV = dK + 512;
#pragma unroll
        for (int r = 0; r < 2; ++r) {
            glds16(gkh + r * 256 + tid, dK + r * 256);
            glds16(gvh + r * 256 + tid, dV + r * 256);
        }
    };

    STAGE(0, 0);

    for (int h = 0; h < HALVES; ++h) {
        __builtin_amdgcn_s_barrier();            // prev compute done
        if (h + 1 < HALVES) {
            STAGE(h + 1, (h + 1) & 1);
            asm volatile("s_waitcnt vmcnt(4)" ::: "memory");  // buf[h] landed (mine)
        } else {
            asm volatile("s_waitcnt vmcnt(0)" ::: "memory");
        }
        __builtin_amdgcn_s_barrier();            // buf[h] landed (everyone)

        const uint4* bK = sm + ((h & 1) << 10);
        const uint4* bV = bK + 512;
#pragma unroll
        for (int t0 = 0; t0 < HALF / 32; ++t0) {
            const int t = (t0 + wv) & (HALF / 32 - 1);   // wave-staggered tile order
            U4 ka0, ka1, vb0, vb1;
            ka0.q = bK[t * 128 + lane];
            ka1.q = bK[t * 128 + 64 + lane];
            vb0.q = bV[t * 128 + lane];
            vb1.q = bV[t * 128 + 64 + lane];

            f32x16 s;
            s = __builtin_amdgcn_mfma_f32_32x32x16_bf16(ka0.v, q0.v, z16, 0, 0, 0);
            s = __builtin_amdgcn_mfma_f32_32x32x16_bf16(ka1.v, q1.v, s, 0, 0, 0);
            // lane holds P[i = crow(r,hi), j = lo]
            float p[16];
#pragma unroll
            for (int r = 0; r < 16; ++r) p[r] = exp2poly(s[r]);

#pragma unroll
            for (int ks = 0; ks < 2; ++ks) {
                const float* pb = p + ks * 8;
                unsigned a0 = cvtpk(pb[0], pb[1]);
                unsigned a1 = cvtpk(pb[2], pb[3]);
                unsigned b0 = cvtpk(pb[4], pb[5]);
                unsigned b1 = cvtpk(pb[6], pb[7]);
                unsigned w01, w45, w23, w67;
                swap32(a0, b0, w01, w45);
                swap32(a1, b1, w23, w67);
                U4 pa;
                pa.q = make_uint4(w01, w23, w45, w67);
                y = __builtin_amdgcn_mfma_f32_32x32x16_bf16(
                        pa.v, (ks ? vb1.v : vb0.v), y, 0, 0, 0);
                dg16 = __builtin_amdgcn_mfma_f32_32x32x16_bf16(
                        pa.v, ones.v, dg16, 0, 0, 0);
            }
        }
    }

    // dense partial stores
    float* yrow = party + ((size_t)chunk * NPIX + (size_t)jblk * 32) * 32;
    float* drow = partd + (size_t)chunk * NPIX + (size_t)jblk * 32;
#pragma unroll
    for (int r = 0; r < 16; ++r) {
        int jr = (r & 3) + 8 * (r >> 2) + 4 * hi;
        yrow[(size_t)jr * 32 + lo] = y[r];
        if (lo == 0) drow[jr] = dg16[r];
    }
}

// ---------------- prep: x_in [32][8192] -> master [j][32] + permuted bf16 ----------------
__global__ __launch_bounds__(256) void k_prep(const float* __restrict__ xin,
                                              float* __restrict__ xm,
                                              unsigned short* __restrict__ kq,
                                              unsigned short* __restrict__ vv) {
    const int j = blockIdx.x * 256 + threadIdx.x;
    float xv[DIM];
#pragma unroll
    for (int d = 0; d < DIM; ++d) xv[d] = xin[(size_t)d * NPIX + j];

    float4* xmr = (float4*)(xm + (size_t)j * DIM);
#pragma unroll
    for (int q = 0; q < 8; ++q)
        xmr[q] = make_float4(xv[4*q], xv[4*q+1], xv[4*q+2], xv[4*q+3]);

    uint4* kq4 = (uint4*)kq;
#pragma unroll
    for (int ks = 0; ks < 2; ++ks)
#pragma unroll
        for (int h = 0; h < 2; ++h) {
            const int b = ks * 16 + h * 8;
            kq4[(j >> 5) * 128 + ks * 64 + h * 32 + (j & 31)] =
                make_uint4(pk2(xv[b+0]*ALPHA, xv[b+1]*ALPHA), pk2(xv[b+2]*ALPHA, xv[b+3]*ALPHA),
                           pk2(xv[b+4]*ALPHA, xv[b+5]*ALPHA), pk2(xv[b+6]*ALPHA, xv[b+7]*ALPHA));
        }

    const int vbase = (j >> 5) * 1024 + ((j >> 4) & 1) * 512 + ((j >> 3) & 1) * 256 + (j & 7);
#pragma unroll
    for (int d = 0; d < DIM; ++d) vv[vbase + d * 8] = f2bf(xv[d]);
}

// ---------------- reduce + blend + regenerate, 4 threads per j ----------------
__global__ __launch_bounds__(256) void k_upd(const float* __restrict__ party,
                                             const float* __restrict__ partd,
                                             const float* __restrict__ xm,
                                             float* __restrict__ xm_next,
                                             unsigned short* __restrict__ kq,
                                             unsigned short* __restrict__ vv,
                                             float* __restrict__ out,
                                             int last) {
    const int t = blockIdx.x * 256 + threadIdx.x;   // 0..32767
    const int j = t >> 2, q = t & 3;                // q: which 8-dim slice

    float4 ya = make_float4(0.f, 0.f, 0.f, 0.f);
    float4 yb = make_float4(0.f, 0.f, 0.f, 0.f);
    float dg = 0.f;
    for (int c = 0; c < SCH; ++c) {
        const float4* p4 = (const float4*)(party + ((size_t)c * NPIX + j) * 32 + q * 8);
        float4 a = p4[0], b = p4[1];
        ya.x += a.x; ya.y += a.y; ya.z += a.z; ya.w += a.w;
        yb.x += b.x; yb.y += b.y; yb.z += b.z; yb.w += b.w;
        dg += partd[(size_t)c * NPIX + j];
    }
    const float inv = 0.5f / dg;

    const float4* xr = (const float4*)(xm + (size_t)j * DIM + q * 8);
    float4 v0 = xr[0], v1 = xr[1];
    float xn[8];
    xn[0] = fmaf(ya.x, inv, 0.5f * v0.x);
    xn[1] = fmaf(ya.y, inv, 0.5f * v0.y);
    xn[2] = fmaf(ya.z, inv, 0.5f * v0.z);
    xn[3] = fmaf(ya.w, inv, 0.5f * v0.w);
    xn[4] = fmaf(yb.x, inv, 0.5f * v1.x);
    xn[5] = fmaf(yb.y, inv, 0.5f * v1.y);
    xn[6] = fmaf(yb.z, inv, 0.5f * v1.z);
    xn[7] = fmaf(yb.w, inv, 0.5f * v1.w);

    if (last) {
#pragma unroll
        for (int e = 0; e < 8; ++e) out[(size_t)(q * 8 + e) * NPIX + j] = xn[e];
        return;
    }

    float4* xw = (float4*)(xm_next + (size_t)j * DIM + q * 8);
    xw[0] = make_float4(xn[0], xn[1], xn[2], xn[3]);
    xw[1] = make_float4(xn[4], xn[5], xn[6], xn[7]);

    ((uint4*)kq)[(j >> 5) * 128 + (q >> 1) * 64 + (q & 1) * 32 + (j & 31)] =
        make_uint4(pk2(xn[0]*ALPHA, xn[1]*ALPHA), pk2(xn[2]*ALPHA, xn[3]*ALPHA),
                   pk2(xn[4]*ALPHA, xn[5]*ALPHA), pk2(xn[6]*ALPHA, xn[7]*ALPHA));

    const int vbase = (j >> 5) * 1024 + ((j >> 4) & 1) * 512 + ((j >> 3) & 1) * 256 + (j & 7);
#pragma unroll
    for (int e = 0; e < 8; ++e) vv[vbase + (q * 8 + e) * 8] = f2bf(xn[e]);
}

extern "C" void kernel_launch(void* const* d_in, const int* in_sizes, int n_in,
                              void* d_out, int out_size, void* d_ws, size_t ws_size,
                              hipStream_t stream) {
    const float* x_in = (const float*)d_in[0];
    float* out = (float*)d_out;

    const size_t nd = (size_t)NPIX * DIM;            // 262144
    float* xmA = (float*)d_ws;
    float* xmB = xmA + nd;
    float* party = xmB + nd;                         // SCH*8192*32 f32 (16.8 MB)
    float* partd = party + (size_t)SCH * NPIX * 32;  // SCH*8192 f32
    unsigned short* kq = (unsigned short*)(partd + (size_t)SCH * NPIX);
    unsigned short* vv = kq + nd;

    k_prep<<<NPIX / 256, 256, 0, stream>>>(x_in, xmA, kq, vv);

    for (int it = 0; it < NITER; ++it) {
        const int last = (it == NITER - 1);
        k_ms<<<dim3(NPIX / (32 * WAVES), SCH), 256, 0, stream>>>(kq, vv, party, partd);
        k_upd<<<(NPIX * 4) / 256, 256, 0, stream>>>(party, partd, xmA, xmB, kq, vv, out, last);
        float* t = xmA; xmA = xmB; xmB = t;
    }
}

// Round 12
// 109.574 us; speedup vs baseline: 1.4071x; 1.4071x over previous
//
#include <hip/hip_runtime.h>
#include <hip/hip_bf16.h>
#include <math.h>

// Mean-shift as attention. Round 12 = round-10 structure, v_exp_f32 restored
// (round-11 poly regression proved VALU issue is the marginal constraint), two
// HBM-traffic cuts that leave the per-wave instruction stream unchanged:
//  - WAVES=8 (512-thread WG): one staged chunk serves 256 j -> fetch 64->32MB.
//    Grid 512 = 2 WGs/CU x 8 waves = same 4 waves/SIMD; launch_bounds(512,4)
//    keeps the 128-VGPR cap.
//  - party partials in bf16 (y error ~1e-6 in xn): 16.8 -> 8.4 MB + half the
//    k_upd read traffic. dg partials stay f32.

typedef short bf16x8 __attribute__((ext_vector_type(8)));
typedef float f32x16 __attribute__((ext_vector_type(16)));
typedef int v2i __attribute__((ext_vector_type(2)));

#define NPIX 8192
#define DIM 32
#define NITER 5
#define SCH 16                // i-chunks (grid.y)
#define CHUNK (NPIX / SCH)    // 512 i per WG
#define HALF 128              // i per LDS stage
#define HALVES (CHUNK / HALF) // 4
#define WAVES 8               // waves per WG (256 j per WG)
#define ALPHA 0.8493219f      // sqrt(0.5 * log2(e))

#if __has_builtin(__builtin_amdgcn_exp2f)
#define EXP2(x) __builtin_amdgcn_exp2f(x)
#else
#define EXP2(x) exp2f(x)
#endif

__device__ __forceinline__ void glds16(const uint4* g, uint4* l) {
#if __has_builtin(__builtin_amdgcn_global_load_lds)
    __builtin_amdgcn_global_load_lds((const __attribute__((address_space(1))) void*)g,
                                     (__attribute__((address_space(3))) void*)l,
                                     16, 0, 0);
#else
    *l = *g;
#endif
}

__device__ inline unsigned cvtpk(float lo, float hi) {
    unsigned r;
    asm("v_cvt_pk_bf16_f32 %0, %1, %2" : "=v"(r) : "v"(lo), "v"(hi));
    return r;
}

__device__ inline void swap32(unsigned a, unsigned b, unsigned& x, unsigned& y) {
#if __has_builtin(__builtin_amdgcn_permlane32_swap)
    v2i r = __builtin_amdgcn_permlane32_swap((int)a, (int)b, false, false);
    x = (unsigned)r.x;
    y = (unsigned)r.y;
#else
    unsigned bs = __shfl_xor(b, 32);
    unsigned as = __shfl_xor(a, 32);
    int hi = (int)(threadIdx.x & 63) >> 5;
    x = hi ? bs : a;
    y = hi ? b : as;
#endif
}

__device__ inline unsigned short f2bf(float f) {  // RNE
    unsigned u = __float_as_uint(f);
    unsigned r = (u + 0x7FFFu + ((u >> 16) & 1u)) >> 16;
    return (unsigned short)r;
}

__device__ inline unsigned pk2(float a, float b) {
    return (unsigned)f2bf(a) | ((unsigned)f2bf(b) << 16);
}

__device__ inline float bfl(unsigned u) { return __uint_as_float(u << 16); }
__device__ inline float bfh(unsigned u) { return __uint_as_float(u & 0xFFFF0000u); }

union U4 { uint4 q; bf16x8 v; };

// ---------------- main pair kernel ----------------
__global__ __launch_bounds__(512, 4) void k_ms(const unsigned short* __restrict__ kq,
                                               const unsigned short* __restrict__ vv,
                                               unsigned short* __restrict__ party,
                                               float* __restrict__ partd) {
    __shared__ uint4 sm[2048];  // 2 bufs x (K 512 | V 512) uint4 = 32 KB
    const int tid = threadIdx.x;
    const int lane = tid & 63;
    const int lo = lane & 31, hi = lane >> 5;
    const int wv = tid >> 6;
    const int wbase = tid & ~63;
    const int jblk = blockIdx.x * WAVES + wv;   // 0..255
    const int chunk = blockIdx.y;               // 0..SCH-1

    const uint4* kq4 = (const uint4*)kq;
    const uint4* vv4 = (const uint4*)vv;

    U4 q0, q1;
    q0.q = kq4[jblk * 128 + lane];
    q1.q = kq4[jblk * 128 + 64 + lane];

    U4 ones;
    ones.q = make_uint4(0x3F803F80u, 0x3F803F80u, 0x3F803F80u, 0x3F803F80u);

    f32x16 z16;
#pragma unroll
    for (int r = 0; r < 16; ++r) z16[r] = 0.f;
    f32x16 y = z16;
    f32x16 dg16 = z16;

    const uint4* gk = kq4 + (size_t)chunk * CHUNK * 4;   // 64 B per i
    const uint4* gv = vv4 + (size_t)chunk * CHUNK * 4;

    // 512 threads stage one 8KB K-half + 8KB V-half in ONE glds each
    auto STAGE = [&](int h, int b) {
        const uint4* gkh = gk + h * (HALF * 4);
        const uint4* gvh = gv + h * (HALF * 4);
        uint4* dK = sm + b * 1024 + wbase;   // wave-uniform LDS base
        glds16(gkh + tid, dK);
        glds16(gvh + tid, dK + 512);
    };

    STAGE(0, 0);

    for (int h = 0; h < HALVES; ++h) {
        __builtin_amdgcn_s_barrier();            // prev compute done
        if (h + 1 < HALVES) {
            STAGE(h + 1, (h + 1) & 1);
            asm volatile("s_waitcnt vmcnt(2)" ::: "memory");  // buf[h] landed (mine)
        } else {
            asm volatile("s_waitcnt vmcnt(0)" ::: "memory");
        }
        __builtin_amdgcn_s_barrier();            // buf[h] landed (everyone)

        const uint4* bK = sm + ((h & 1) << 10);
        const uint4* bV = bK + 512;
#pragma unroll
        for (int t = 0; t < HALF / 32; ++t) {
            U4 ka0, ka1, vb0, vb1;
            ka0.q = bK[t * 128 + lane];
            ka1.q = bK[t * 128 + 64 + lane];
            vb0.q = bV[t * 128 + lane];
            vb1.q = bV[t * 128 + 64 + lane];

            f32x16 s;
            s = __builtin_amdgcn_mfma_f32_32x32x16_bf16(ka0.v, q0.v, z16, 0, 0, 0);
            s = __builtin_amdgcn_mfma_f32_32x32x16_bf16(ka1.v, q1.v, s, 0, 0, 0);
            // lane holds P[i = crow(r,hi), j = lo]
            float p[16];
#pragma unroll
            for (int r = 0; r < 16; ++r) p[r] = EXP2(s[r]);

#pragma unroll
            for (int ks = 0; ks < 2; ++ks) {
                const float* pb = p + ks * 8;
                unsigned a0 = cvtpk(pb[0], pb[1]);
                unsigned a1 = cvtpk(pb[2], pb[3]);
                unsigned b0 = cvtpk(pb[4], pb[5]);
                unsigned b1 = cvtpk(pb[6], pb[7]);
                unsigned w01, w45, w23, w67;
                swap32(a0, b0, w01, w45);
                swap32(a1, b1, w23, w67);
                U4 pa;
                pa.q = make_uint4(w01, w23, w45, w67);
                y = __builtin_amdgcn_mfma_f32_32x32x16_bf16(
                        pa.v, (ks ? vb1.v : vb0.v), y, 0, 0, 0);
                dg16 = __builtin_amdgcn_mfma_f32_32x32x16_bf16(
                        pa.v, ones.v, dg16, 0, 0, 0);
            }
        }
    }

    // partial stores: y as bf16 (coalesced 64B rows), dg as f32
    unsigned short* yrow = party + ((size_t)chunk * NPIX + (size_t)jblk * 32) * 32;
    float* drow = partd + (size_t)chunk * NPIX + (size_t)jblk * 32;
#pragma unroll
    for (int r = 0; r < 16; ++r) {
        int jr = (r & 3) + 8 * (r >> 2) + 4 * hi;
        yrow[(size_t)jr * 32 + lo] = f2bf(y[r]);
        if (lo == 0) drow[jr] = dg16[r];
    }
}

// ---------------- prep: x_in [32][8192] -> master [j][32] + permuted bf16 ----------------
__global__ __launch_bounds__(256) void k_prep(const float* __restrict__ xin,
                                              float* __restrict__ xm,
                                              unsigned short* __restrict__ kq,
                                              unsigned short* __restrict__ vv) {
    const int j = blockIdx.x * 256 + threadIdx.x;
    float xv[DIM];
#pragma unroll
    for (int d = 0; d < DIM; ++d) xv[d] = xin[(size_t)d * NPIX + j];

    float4* xmr = (float4*)(xm + (size_t)j * DIM);
#pragma unroll
    for (int q = 0; q < 8; ++q)
        xmr[q] = make_float4(xv[4*q], xv[4*q+1], xv[4*q+2], xv[4*q+3]);

    uint4* kq4 = (uint4*)kq;
#pragma unroll
    for (int ks = 0; ks < 2; ++ks)
#pragma unroll
        for (int h = 0; h < 2; ++h) {
            const int b = ks * 16 + h * 8;
            kq4[(j >> 5) * 128 + ks * 64 + h * 32 + (j & 31)] =
                make_uint4(pk2(xv[b+0]*ALPHA, xv[b+1]*ALPHA), pk2(xv[b+2]*ALPHA, xv[b+3]*ALPHA),
                           pk2(xv[b+4]*ALPHA, xv[b+5]*ALPHA), pk2(xv[b+6]*ALPHA, xv[b+7]*ALPHA));
        }

    const int vbase = (j >> 5) * 1024 + ((j >> 4) & 1) * 512 + ((j >> 3) & 1) * 256 + (j & 7);
#pragma unroll
    for (int d = 0; d < DIM; ++d) vv[vbase + d * 8] = f2bf(xv[d]);
}

// ---------------- reduce + blend + regenerate, 4 threads per j ----------------
__global__ __launch_bounds__(256) void k_upd(const unsigned short* __restrict__ party,
                                             const float* __restrict__ partd,
                                             const float* __restrict__ xm,
                                             float* __restrict__ xm_next,
                                             unsigned short* __restrict__ kq,
                                             unsigned short* __restrict__ vv,
                                             float* __restrict__ out,
                                             int last) {
    const int t = blockIdx.x * 256 + threadIdx.x;   // 0..32767
    const int j = t >> 2, q = t & 3;                // q: which 8-dim slice

    float ys[8];
#pragma unroll
    for (int e = 0; e < 8; ++e) ys[e] = 0.f;
    float dg = 0.f;
    for (int c = 0; c < SCH; ++c) {
        uint4 u = *(const uint4*)(party + ((size_t)c * NPIX + j) * 32 + q * 8);
        ys[0] += bfl(u.x); ys[1] += bfh(u.x);
        ys[2] += bfl(u.y); ys[3] += bfh(u.y);
        ys[4] += bfl(u.z); ys[5] += bfh(u.z);
        ys[6] += bfl(u.w); ys[7] += bfh(u.w);
        dg += partd[(size_t)c * NPIX + j];
    }
    const float inv = 0.5f / dg;

    const float4* xr = (const float4*)(xm + (size_t)j * DIM + q * 8);
    float4 v0 = xr[0], v1 = xr[1];
    float xn[8];
    xn[0] = fmaf(ys[0], inv, 0.5f * v0.x);
    xn[1] = fmaf(ys[1], inv, 0.5f * v0.y);
    xn[2] = fmaf(ys[2], inv, 0.5f * v0.z);
    xn[3] = fmaf(ys[3], inv, 0.5f * v0.w);
    xn[4] = fmaf(ys[4], inv, 0.5f * v1.x);
    xn[5] = fmaf(ys[5], inv, 0.5f * v1.y);
    xn[6] = fmaf(ys[6], inv, 0.5f * v1.z);
    xn[7] = fmaf(ys[7], inv, 0.5f * v1.w);

    if (last) {
#pragma unroll
        for (int e = 0; e < 8; ++e) out[(size_t)(q * 8 + e) * NPIX + j] = xn[e];
        return;
    }

    float4* xw = (float4*)(xm_next + (size_t)j * DIM + q * 8);
    xw[0] = make_float4(xn[0], xn[1], xn[2], xn[3]);
    xw[1] = make_float4(xn[4], xn[5], xn[6], xn[7]);

    ((uint4*)kq)[(j >> 5) * 128 + (q >> 1) * 64 + (q & 1) * 32 + (j & 31)] =
        make_uint4(pk2(xn[0]*ALPHA, xn[1]*ALPHA), pk2(xn[2]*ALPHA, xn[3]*ALPHA),
                   pk2(xn[4]*ALPHA, xn[5]*ALPHA), pk2(xn[6]*ALPHA, xn[7]*ALPHA));

    const int vbase = (j >> 5) * 1024 + ((j >> 4) & 1) * 512 + ((j >> 3) & 1) * 256 + (j & 7);
#pragma unroll
    for (int e = 0; e < 8; ++e) vv[vbase + (q * 8 + e) * 8] = f2bf(xn[e]);
}

extern "C" void kernel_launch(void* const* d_in, const int* in_sizes, int n_in,
                              void* d_out, int out_size, void* d_ws, size_t ws_size,
                              hipStream_t stream) {
    const float* x_in = (const float*)d_in[0];
    float* out = (float*)d_out;

    const size_t nd = (size_t)NPIX * DIM;            // 262144
    float* xmA = (float*)d_ws;
    float* xmB = xmA + nd;
    unsigned short* party = (unsigned short*)(xmB + nd);   // SCH*8192*32 bf16 (8.4 MB)
    float* partd = (float*)(party + (size_t)SCH * NPIX * 32);  // SCH*8192 f32
    unsigned short* kq = (unsigned short*)(partd + (size_t)SCH * NPIX);
    unsigned short* vv = kq + nd;

    k_prep<<<NPIX / 256, 256, 0, stream>>>(x_in, xmA, kq, vv);

    for (int it = 0; it < NITER; ++it) {
        const int last = (it == NITER - 1);
        k_ms<<<dim3(NPIX / (32 * WAVES), SCH), 512, 0, stream>>>(kq, vv, party, partd);
        k_upd<<<(NPIX * 4) / 256, 256, 0, stream>>>(party, partd, xmA, xmB, kq, vv, out, last);
        float* t = xmA; xmA = xmB; xmB = t;
    }
}